// Round 2
// baseline (488.811 us; speedup 1.0000x reference)
//
#include <hip/hip_runtime.h>
#include <hip/hip_bf16.h>

// Problem constants
#define B_    16384
#define F_    32
#define E_    16
#define V_    100000
#define D_    4
#define S_    8
#define K_    2
#define I_    512
#define OUT_  16
#define SK_   10
#define C_    192      // padded fold-matrix columns (160 expert outs + 10 gate + 22 pad)
#define OSTR  193      // obuf LDS row stride (conflict-free)
#define EPS_  1e-5f

// ---------- helpers ----------
__device__ __forceinline__ unsigned short f2bf(float x) {
    unsigned u = __float_as_uint(x);
    unsigned r = (u + 0x7fffu + ((u >> 16) & 1u)) >> 16;
    return (unsigned short)r;
}
__device__ __forceinline__ float bflo(unsigned u) { return __uint_as_float(u << 16); }
__device__ __forceinline__ float bfhi(unsigned u) { return __uint_as_float(u & 0xffff0000u); }

// ---------- K1: embedding gather + per-domain moment accumulation ----------
__global__ __launch_bounds__(256) void k_gather(
    const int* __restrict__ ids, const int* __restrict__ dom,
    const float* __restrict__ tbl, unsigned short* __restrict__ emb,
    float* __restrict__ S1, float* __restrict__ S2)
{
    const int t = threadIdx.x;
    const int slot = t & 127;     // owns cols slot*4 .. slot*4+3
    const int rsub = t >> 7;      // row parity within pair
    const int f = slot >> 2;
    const int e0 = (slot & 3) << 2;
    float sa[4][4], qa[4][4];
#pragma unroll
    for (int d = 0; d < 4; ++d)
#pragma unroll
        for (int c = 0; c < 4; ++c) { sa[d][c] = 0.f; qa[d][c] = 0.f; }

    const float* fbase = tbl + (size_t)f * V_ * E_ + e0;
    for (int r0 = blockIdx.x * 2; r0 < B_; r0 += gridDim.x * 2) {
        const int r = r0 + rsub;
        const int id = ids[r * F_ + f];
        const float4 v = *(const float4*)(fbase + (size_t)id * E_);
        const int d = dom[r];
        unsigned p0 = (unsigned)f2bf(v.x) | ((unsigned)f2bf(v.y) << 16);
        unsigned p1 = (unsigned)f2bf(v.z) | ((unsigned)f2bf(v.w) << 16);
        *(uint2*)(emb + (size_t)r * I_ + slot * 4) = make_uint2(p0, p1);
#pragma unroll
        for (int dd = 0; dd < 4; ++dd) {
            const float m = (d == dd) ? 1.f : 0.f;
            sa[dd][0] = fmaf(m, v.x, sa[dd][0]); qa[dd][0] = fmaf(m * v.x, v.x, qa[dd][0]);
            sa[dd][1] = fmaf(m, v.y, sa[dd][1]); qa[dd][1] = fmaf(m * v.y, v.y, qa[dd][1]);
            sa[dd][2] = fmaf(m, v.z, sa[dd][2]); qa[dd][2] = fmaf(m * v.z, v.z, qa[dd][2]);
            sa[dd][3] = fmaf(m, v.w, sa[dd][3]); qa[dd][3] = fmaf(m * v.w, v.w, qa[dd][3]);
        }
    }
    __shared__ float red[128][33];
    if (rsub) {
        float* p = red[slot];
#pragma unroll
        for (int d = 0; d < 4; ++d)
#pragma unroll
            for (int c = 0; c < 4; ++c) { p[d * 4 + c] = sa[d][c]; p[16 + d * 4 + c] = qa[d][c]; }
    }
    __syncthreads();
    if (!rsub) {
        float* p = red[slot];
#pragma unroll
        for (int d = 0; d < 4; ++d)
#pragma unroll
            for (int c = 0; c < 4; ++c) {
                float s = sa[d][c] + p[d * 4 + c];
                float q = qa[d][c] + p[16 + d * 4 + c];
                atomicAdd(&S1[d * I_ + slot * 4 + c], s);
                atomicAdd(&S2[d * I_ + slot * 4 + c], q);
            }
    }
}

// ---------- K2d: bucket rows by domain ----------
__global__ __launch_bounds__(256) void k_bucket(
    const int* __restrict__ dom, int* __restrict__ cnt, int* __restrict__ rl)
{
    const int r = blockIdx.x * 256 + threadIdx.x;
    const int d = dom[r];
    const int lane = threadIdx.x & 63;
#pragma unroll
    for (int dd = 0; dd < 4; ++dd) {
        unsigned long long mask = __ballot(d == dd);
        if (d == dd) {
            int lead = __ffsll((unsigned long long)mask) - 1;
            int pos = 0;
            if (lane == lead) pos = atomicAdd(&cnt[dd], __popcll(mask));
            pos = __shfl(pos, lead);
            pos += __popcll(mask & ((1ull << lane) - 1ull));
            rl[dd * B_ + pos] = r;
        }
    }
}

// ---------- K2a: finalize BN statistics ----------
__global__ __launch_bounds__(512) void k_stats(
    const float* __restrict__ S1, const float* __restrict__ S2, const int* __restrict__ cnt,
    const float* __restrict__ dw, const float* __restrict__ db,
    float* __restrict__ m_, float* __restrict__ dq, float* __restrict__ mu, float* __restrict__ isg)
{
    const int i = threadIdx.x;
    float nd[4], s1v[4], s2v[4], wv[4], bv[4];
#pragma unroll
    for (int d = 0; d < 4; ++d) {
        nd[d] = (float)cnt[d];
        s1v[d] = S1[d * I_ + i]; s2v[d] = S2[d * I_ + i];
        wv[d] = dw[d * I_ + i];  bv[d] = db[d * I_ + i];
    }
    const float invB = 1.0f / (float)B_;
    float tot1 = s1v[0] + s1v[1] + s1v[2] + s1v[3];
    float tot2 = s2v[0] + s2v[1] + s2v[2] + s2v[3];
    float m = tot1 * invB;
    float v = fmaxf(tot2 * invB - m * m, 0.f);
    m_[i] = m;
#pragma unroll
    for (int d = 0; d < 4; ++d)
        dq[d * I_ + i] = wv[d] / sqrtf(v * wv[d] * wv[d] + EPS_);
    float ssum = 0.f, ssq = 0.f;
#pragma unroll
    for (int d = 0; d < 4; ++d) {
        ssum += wv[d] * s1v[d] + nd[d] * bv[d];
        ssq  += wv[d] * wv[d] * s2v[d] + 2.f * wv[d] * bv[d] * s1v[d] + nd[d] * bv[d] * bv[d];
    }
    float muv = ssum * invB;
    float var = fmaxf(ssq * invB - muv * muv, 0.f);
    mu[i] = muv;
    isg[i] = 1.f / sqrtf(var + EPS_);
}

// ---------- K2b: fold all expert weights into per-domain matrix M[d][512][192] ----------
__global__ __launch_bounds__(256) void k_foldM(
    const float* __restrict__ dw, const float* __restrict__ isg, const float* __restrict__ dq,
    const float* __restrict__ shg, const float* __restrict__ shW,
    const float* __restrict__ spg, const float* __restrict__ spW,
    const float* __restrict__ gW, float* __restrict__ M)
{
    const int d = blockIdx.y;
    const int c = threadIdx.x;
    if (c >= C_) return;
    const int i0 = blockIdx.x * 32;
    for (int i = i0; i < i0 + 32; ++i) {
        float val = 0.f;
        if (c < 128) {
            const int s = c >> 4, o = c & 15;
            val = dw[d * I_ + i] * isg[i] * shg[s * I_ + i] * shW[((size_t)s * I_ + i) * OUT_ + o];
        } else if (c < 160) {
            const int k = (c - 128) >> 4, o = c & 15;
            val = dq[d * I_ + i] * spg[((size_t)(d * K_ + k)) * I_ + i]
                * spW[(((size_t)(d * K_ + k)) * I_ + i) * OUT_ + o];
        } else if (c < 170) {
            val = dw[d * I_ + i] * gW[i * SK_ + (c - 160)];
        }
        M[((size_t)d * I_ + i) * C_ + c] = val;
    }
}

// ---------- K2c: fold biases ----------
__global__ __launch_bounds__(256) void k_foldB(
    const float* __restrict__ m_, const float* __restrict__ dq,
    const float* __restrict__ mu, const float* __restrict__ isg,
    const float* __restrict__ db,
    const float* __restrict__ shg, const float* __restrict__ shb_, const float* __restrict__ shW,
    const float* __restrict__ shb2,
    const float* __restrict__ spg, const float* __restrict__ spb_, const float* __restrict__ spW,
    const float* __restrict__ spb2,
    const float* __restrict__ gW, const float* __restrict__ gb, float* __restrict__ bias)
{
    const int d = blockIdx.y, e = blockIdx.x, t = threadIdx.x;
    __shared__ float red[256][17];
    float acc[16];
#pragma unroll
    for (int o = 0; o < 16; ++o) acc[o] = 0.f;

    if (e < 8) {
        for (int i = t; i < I_; i += 256) {
            float coef = (db[d * I_ + i] - mu[i]) * isg[i] * shg[e * I_ + i] + shb_[e * I_ + i];
            const float* wp = &shW[((size_t)e * I_ + i) * OUT_];
#pragma unroll
            for (int o = 0; o < 16; ++o) acc[o] += coef * wp[o];
        }
    } else if (e < 10) {
        const int k = e - 8;
        for (int i = t; i < I_; i += 256) {
            float coef = -m_[i] * dq[d * I_ + i] * spg[((size_t)(d * K_ + k)) * I_ + i]
                       + spb_[((size_t)(d * K_ + k)) * I_ + i];
            const float* wp = &spW[(((size_t)(d * K_ + k)) * I_ + i) * OUT_];
#pragma unroll
            for (int o = 0; o < 16; ++o) acc[o] += coef * wp[o];
        }
    } else {
        for (int i = t; i < I_; i += 256) {
            float bb = db[d * I_ + i];
#pragma unroll
            for (int g = 0; g < 10; ++g) acc[g] += bb * gW[i * SK_ + g];
        }
    }
#pragma unroll
    for (int o = 0; o < 16; ++o) red[t][o] = acc[o];
    __syncthreads();
    for (int st = 128; st > 0; st >>= 1) {
        if (t < st) {
#pragma unroll
            for (int o = 0; o < 16; ++o) red[t][o] += red[t + st][o];
        }
        __syncthreads();
    }
    if (t == 0) {
        if (e < 8) {
            for (int o = 0; o < 16; ++o) bias[d * C_ + e * 16 + o] = red[0][o] + shb2[e * 16 + o];
        } else if (e < 10) {
            const int k = e - 8;
            for (int o = 0; o < 16; ++o)
                bias[d * C_ + 128 + k * 16 + o] = red[0][o] + spb2[(d * K_ + k) * 16 + o];
        } else {
            for (int g = 0; g < 10; ++g) bias[d * C_ + 160 + g] = red[0][g] + gb[g];
            for (int c = 170; c < C_; ++c) bias[d * C_ + c] = 0.f;
        }
    }
}

// ---------- K3: main fused GEMM + softmax gate + mix + MLP layer 1 ----------
__global__ __launch_bounds__(256) void k_main(
    const unsigned short* __restrict__ emb, const int* __restrict__ rl, const int* __restrict__ cnt,
    const float* __restrict__ M, const float* __restrict__ bias,
    const float* __restrict__ W1, const float* __restrict__ b1,
    float* __restrict__ h1g, float* __restrict__ h1s, float* __restrict__ h1q)
{
    const int d = blockIdx.y, tile = blockIdx.x;
    const int base = tile * 64;
    const int rem = cnt[d] - base;
    if (rem <= 0) return;
    const int nn = rem < 64 ? rem : 64;
    const int t = threadIdx.x;

    __shared__ int rid[64];
    __shared__ float smem[64 * OSTR + 64 * 33];   // obuf | h1buf (ebuf+mbuf alias obuf head)
    float* ebuf = smem;                 // [32][64]
    float* mbuf = smem + 2048;          // [32][192]
    float* obuf = smem;                 // [64][OSTR]
    float* h1buf = smem + 64 * OSTR;    // [64][33]

    if (t < 64) rid[t] = rl[d * B_ + base + (t < nn ? t : nn - 1)];
    __syncthreads();

    float acc[4][12];
#pragma unroll
    for (int j = 0; j < 4; ++j)
#pragma unroll
        for (int q = 0; q < 12; ++q) acc[j][q] = 0.f;

    const int rgrp = t >> 4, cgrp = t & 15;
    const int lrow = t >> 2, lpart = t & 3;
    const float* Md = M + (size_t)d * I_ * C_;
    const size_t ebase = (size_t)rid[lrow] * I_ + lpart * 8;

    for (int ic = 0; ic < 16; ++ic) {
        // stage 64x32 emb slice (bf16 -> f32), layout ebuf[i][row]
        uint4 u = *(const uint4*)(emb + ebase + ic * 32);
        {
            const int ib = lpart * 8;
            ebuf[(ib + 0) * 64 + lrow] = bflo(u.x);
            ebuf[(ib + 1) * 64 + lrow] = bfhi(u.x);
            ebuf[(ib + 2) * 64 + lrow] = bflo(u.y);
            ebuf[(ib + 3) * 64 + lrow] = bfhi(u.y);
            ebuf[(ib + 4) * 64 + lrow] = bflo(u.z);
            ebuf[(ib + 5) * 64 + lrow] = bfhi(u.z);
            ebuf[(ib + 6) * 64 + lrow] = bflo(u.w);
            ebuf[(ib + 7) * 64 + lrow] = bfhi(u.w);
        }
        // stage 32x192 M slice
        const float* Msrc = Md + (size_t)ic * 32 * C_;
#pragma unroll
        for (int k = 0; k < 6; ++k) {
            const int fi = k * 256 + t;
            *(float4*)&mbuf[fi * 4] = *(const float4*)(Msrc + fi * 4);
        }
        __syncthreads();
#pragma unroll 8
        for (int i = 0; i < 32; ++i) {
            const float4 e4 = *(const float4*)&ebuf[i * 64 + rgrp * 4];
            const float4 ma = *(const float4*)&mbuf[i * C_ + cgrp * 12];
            const float4 mb = *(const float4*)&mbuf[i * C_ + cgrp * 12 + 4];
            const float4 mc = *(const float4*)&mbuf[i * C_ + cgrp * 12 + 8];
#define ROWFMA(j, ej) \
            acc[j][0] = fmaf(ej, ma.x, acc[j][0]); acc[j][1] = fmaf(ej, ma.y, acc[j][1]); \
            acc[j][2] = fmaf(ej, ma.z, acc[j][2]); acc[j][3] = fmaf(ej, ma.w, acc[j][3]); \
            acc[j][4] = fmaf(ej, mb.x, acc[j][4]); acc[j][5] = fmaf(ej, mb.y, acc[j][5]); \
            acc[j][6] = fmaf(ej, mb.z, acc[j][6]); acc[j][7] = fmaf(ej, mb.w, acc[j][7]); \
            acc[j][8] = fmaf(ej, mc.x, acc[j][8]); acc[j][9] = fmaf(ej, mc.y, acc[j][9]); \
            acc[j][10] = fmaf(ej, mc.z, acc[j][10]); acc[j][11] = fmaf(ej, mc.w, acc[j][11]);
            ROWFMA(0, e4.x) ROWFMA(1, e4.y) ROWFMA(2, e4.z) ROWFMA(3, e4.w)
#undef ROWFMA
        }
        __syncthreads();
    }

    // spill to obuf with bias
    const float* bd = bias + d * C_;
#pragma unroll
    for (int j = 0; j < 4; ++j)
#pragma unroll
        for (int q = 0; q < 12; ++q)
            obuf[(rgrp * 4 + j) * OSTR + cgrp * 12 + q] = acc[j][q] + bd[cgrp * 12 + q];
    __syncthreads();

    // per-row: softmax gate, mix, h1 = mix@W1+b1
    if (t < 64) {
        const float* row = &obuf[t * OSTR];
        float g[10];
        float mx = row[160];
#pragma unroll
        for (int e = 1; e < 10; ++e) mx = fmaxf(mx, row[160 + e]);
        float ssum = 0.f;
#pragma unroll
        for (int e = 0; e < 10; ++e) { g[e] = __expf(row[160 + e] - mx); ssum += g[e]; }
        const float inv = 1.f / ssum;
        float mix[16];
#pragma unroll
        for (int o = 0; o < 16; ++o) mix[o] = 0.f;
#pragma unroll
        for (int e = 0; e < 10; ++e) {
#pragma unroll
            for (int o = 0; o < 16; ++o) mix[o] = fmaf(g[e], row[e * 16 + o], mix[o]);
        }
#pragma unroll
        for (int o = 0; o < 16; ++o) mix[o] *= inv;
#pragma unroll
        for (int o2 = 0; o2 < 32; ++o2) {
            float a = b1[o2];
#pragma unroll
            for (int o = 0; o < 16; ++o) a = fmaf(mix[o], W1[o * 32 + o2], a);
            h1buf[t * 33 + o2] = a;
        }
    }
    __syncthreads();
    // h1 batch stats (valid rows only)
    if (t < 32) {
        float s = 0.f, q = 0.f;
        for (int r = 0; r < nn; ++r) { float v = h1buf[r * 33 + t]; s += v; q += v * v; }
        atomicAdd(&h1s[t], s); atomicAdd(&h1q[t], q);
    }
    // write h1 to global (scattered rows)
#pragma unroll
    for (int k = 0; k < 8; ++k) {
        const int idx = k * 256 + t;
        const int r = idx >> 5, c = idx & 31;
        if (r < nn) h1g[(size_t)rid[r] * 32 + c] = h1buf[r * 33 + c];
    }
}

// ---------- K4: BN+ReLU -> x@W2+b2, accumulate h2 stats ----------
__global__ __launch_bounds__(256) void k_mlp1(
    const float* __restrict__ h1g, const float* __restrict__ s1, const float* __restrict__ s2,
    const float* __restrict__ g1, const float* __restrict__ be1,
    const float* __restrict__ W2, const float* __restrict__ b2,
    float* __restrict__ h2g, float* __restrict__ h2s, float* __restrict__ h2q)
{
    __shared__ float hb[64 * 33];
    __shared__ float ab[64 * 33];
    __shared__ float w2t[32 * 32];   // [o][i]
    __shared__ float scl[32], shf[32];
    const int t = threadIdx.x;
    const size_t rb = (size_t)blockIdx.x * 64;
#pragma unroll
    for (int k = 0; k < 2; ++k) {
        const int w = k * 1024 + t * 4;
        const int r = w >> 5, c = w & 31;
        *(float4*)&hb[r * 33 + c] = *(const float4*)&h1g[rb * 32 + w];
    }
#pragma unroll
    for (int k = 0; k < 4; ++k) {
        const int idx = k * 256 + t;
        const int i = idx >> 5, o = idx & 31;
        w2t[o * 32 + i] = W2[idx];
    }
    if (t < 32) {
        const float invB = 1.0f / (float)B_;
        float mn = s1[t] * invB;
        float vr = fmaxf(s2[t] * invB - mn * mn, 0.f);
        float iv = 1.f / sqrtf(vr + EPS_);
        scl[t] = iv * g1[t]; shf[t] = be1[t] - mn * iv * g1[t];
    }
    __syncthreads();
    const int r = t >> 2, sub = t & 3;
#pragma unroll
    for (int k = 0; k < 8; ++k) {
        const int i = sub * 8 + k;
        float x = hb[r * 33 + i] * scl[i] + shf[i];
        ab[r * 33 + i] = fmaxf(x, 0.f);
    }
    __syncthreads();
    float h2[8];
#pragma unroll
    for (int kk = 0; kk < 8; ++kk) {
        const int o = sub * 8 + kk;
        float acc = b2[o];
#pragma unroll
        for (int i = 0; i < 32; i += 4) {
            const float4 w4 = *(const float4*)&w2t[o * 32 + i];
            acc = fmaf(ab[r * 33 + i], w4.x, acc);
            acc = fmaf(ab[r * 33 + i + 1], w4.y, acc);
            acc = fmaf(ab[r * 33 + i + 2], w4.z, acc);
            acc = fmaf(ab[r * 33 + i + 3], w4.w, acc);
        }
        h2[kk] = acc;
    }
    __syncthreads();
#pragma unroll
    for (int kk = 0; kk < 8; ++kk) hb[r * 33 + sub * 8 + kk] = h2[kk];
    __syncthreads();
    if (t < 32) {
        float s = 0.f, q = 0.f;
        for (int rr = 0; rr < 64; ++rr) { float v = hb[rr * 33 + t]; s += v; q += v * v; }
        atomicAdd(&h2s[t], s); atomicAdd(&h2q[t], q);
    }
#pragma unroll
    for (int k = 0; k < 2; ++k) {
        const int w = k * 1024 + t * 4;
        const int r2 = w >> 5, c = w & 31;
        *(float4*)&h2g[rb * 32 + w] = *(const float4*)&hb[r2 * 33 + c];
    }
}

// ---------- K5: BN+ReLU -> x@W3+b3 -> sigmoid ----------
__global__ __launch_bounds__(256) void k_mlp2(
    const float* __restrict__ h2g, const float* __restrict__ s1, const float* __restrict__ s2,
    const float* __restrict__ g2, const float* __restrict__ be2,
    const float* __restrict__ W3, const float* __restrict__ b3, float* __restrict__ out)
{
    __shared__ float hb[64 * 33];
    __shared__ float scl[32], shf[32], w3s[32];
    const int t = threadIdx.x;
    const size_t rb = (size_t)blockIdx.x * 64;
#pragma unroll
    for (int k = 0; k < 2; ++k) {
        const int w = k * 1024 + t * 4;
        const int r = w >> 5, c = w & 31;
        *(float4*)&hb[r * 33 + c] = *(const float4*)&h2g[rb * 32 + w];
    }
    if (t < 32) {
        const float invB = 1.0f / (float)B_;
        float mn = s1[t] * invB;
        float vr = fmaxf(s2[t] * invB - mn * mn, 0.f);
        float iv = 1.f / sqrtf(vr + EPS_);
        scl[t] = iv * g2[t]; shf[t] = be2[t] - mn * iv * g2[t];
        w3s[t] = W3[t];
    }
    __syncthreads();
    if (t < 64) {
        float acc = b3[0];
#pragma unroll
        for (int i = 0; i < 32; ++i) {
            float x = hb[t * 33 + i] * scl[i] + shf[i];
            x = fmaxf(x, 0.f);
            acc = fmaf(x, w3s[i], acc);
        }
        out[rb + t] = 1.f / (1.f + __expf(-acc));
    }
}

// ---------- launch ----------
extern "C" void kernel_launch(void* const* d_in, const int* in_sizes, int n_in,
                              void* d_out, int out_size, void* d_ws, size_t ws_size,
                              hipStream_t stream) {
    const int*   ids  = (const int*)d_in[0];
    const int*   dom  = (const int*)d_in[1];
    const float* tbl  = (const float*)d_in[2];
    const float* dw   = (const float*)d_in[3];
    const float* db   = (const float*)d_in[4];
    const float* shg  = (const float*)d_in[5];
    const float* shb_ = (const float*)d_in[6];
    const float* shW  = (const float*)d_in[7];
    const float* shb2 = (const float*)d_in[8];
    const float* spg  = (const float*)d_in[9];
    const float* spb_ = (const float*)d_in[10];
    const float* spW  = (const float*)d_in[11];
    const float* spb2 = (const float*)d_in[12];
    const float* gW   = (const float*)d_in[13];
    const float* gb   = (const float*)d_in[14];
    const float* W1   = (const float*)d_in[15];
    const float* b1   = (const float*)d_in[16];
    const float* g1   = (const float*)d_in[17];
    const float* be1  = (const float*)d_in[18];
    const float* W2   = (const float*)d_in[19];
    const float* b2   = (const float*)d_in[20];
    const float* g2   = (const float*)d_in[21];
    const float* be2  = (const float*)d_in[22];
    const float* W3   = (const float*)d_in[23];
    const float* b3   = (const float*)d_in[24];
    float* out = (float*)d_out;

    float* ws = (float*)d_ws;
    float* S1   = ws + 0;         // 2048
    float* S2   = ws + 2048;      // 2048
    float* H1S  = ws + 4096;      // 32
    float* H1Q  = ws + 4128;      // 32
    float* H2S  = ws + 4160;      // 32
    float* H2Q  = ws + 4192;      // 32
    int*   CNT  = (int*)(ws + 4224);   // 4 ints
    float* M0v  = ws + 4352;      // 512 (emb col means)
    float* DQ   = ws + 4864;      // 2048
    float* MU   = ws + 6912;      // 512
    float* ISG  = ws + 7424;      // 512
    float* BIASW= ws + 8192;      // 768
    float* MW   = ws + 9216;      // 393216
    int*   RL   = (int*)(ws + 402432);               // 65536 ints
    unsigned short* EMB = (unsigned short*)(ws + 467968);  // 16384*512 bf16
    float* H1G  = ws + 4662272;   // 524288
    float* H2G  = ws + 5186560;   // 524288

    // zero accumulators (S1,S2,h-stats,CNT)
    hipMemsetAsync(d_ws, 0, 17408, stream);

    k_gather<<<256, 256, 0, stream>>>(ids, dom, tbl, EMB, S1, S2);
    k_bucket<<<64, 256, 0, stream>>>(dom, CNT, RL);
    k_stats<<<1, 512, 0, stream>>>(S1, S2, CNT, dw, db, M0v, DQ, MU, ISG);
    k_foldM<<<dim3(16, 4), 256, 0, stream>>>(dw, ISG, DQ, shg, shW, spg, spW, gW, MW);
    k_foldB<<<dim3(11, 4), 256, 0, stream>>>(M0v, DQ, MU, ISG, db, shg, shb_, shW, shb2,
                                             spg, spb_, spW, spb2, gW, gb, BIASW);
    k_main<<<dim3(256, 4), 256, 0, stream>>>(EMB, RL, CNT, MW, BIASW, W1, b1, H1G, H1S, H1Q);
    k_mlp1<<<256, 256, 0, stream>>>(H1G, H1S, H1Q, g1, be1, W2, b2, H2G, H2S, H2Q);
    k_mlp2<<<256, 256, 0, stream>>>(H2G, H2S, H2Q, g2, be2, W3, b3, out);
}

// Round 3
// 403.046 us; speedup vs baseline: 1.2128x; 1.2128x over previous
//
#include <hip/hip_runtime.h>
#include <hip/hip_bf16.h>

// Problem constants
#define B_    16384
#define F_    32
#define E_    16
#define V_    100000
#define D_    4
#define S_    8
#define K_    2
#define I_    512
#define OUT_  16
#define SK_   10
#define C_    192      // padded fold-matrix columns (160 expert outs + 10 gate + 22 pad)
#define OSTR  193      // obuf LDS row stride (conflict-free)
#define EPS_  1e-5f

typedef __attribute__((ext_vector_type(4))) float f32x4;
typedef __attribute__((ext_vector_type(8))) short bf16x8;

// ---------- helpers ----------
__device__ __forceinline__ unsigned short f2bf(float x) {
    unsigned u = __float_as_uint(x);
    unsigned r = (u + 0x7fffu + ((u >> 16) & 1u)) >> 16;
    return (unsigned short)r;
}
__device__ __forceinline__ float bflo(unsigned u) { return __uint_as_float(u << 16); }
__device__ __forceinline__ float bfhi(unsigned u) { return __uint_as_float(u & 0xffff0000u); }

// ---------- K1: embedding gather + per-domain moment accumulation ----------
// 512 blocks x 512 threads (8 waves) -> 2 blocks/CU, 16 waves/CU for MLP.
// Group-split accumulators S1G/S2G[8][4][512] cut atomic contention 8x.
__global__ __launch_bounds__(512) void k_gather(
    const int* __restrict__ ids, const int* __restrict__ dom,
    const float* __restrict__ tbl, unsigned short* __restrict__ emb,
    float* __restrict__ S1G, float* __restrict__ S2G)
{
    const int t = threadIdx.x;
    const int slot = t & 127;     // owns cols slot*4 .. slot*4+3
    const int rsub = t >> 7;      // 0..3
    const int f = slot >> 2;
    const int e0 = (slot & 3) << 2;
    float sa[4][4], qa[4][4];
#pragma unroll
    for (int d = 0; d < 4; ++d)
#pragma unroll
        for (int c = 0; c < 4; ++c) { sa[d][c] = 0.f; qa[d][c] = 0.f; }

    const float* fbase = tbl + (size_t)f * V_ * E_ + e0;
    for (int r0 = blockIdx.x * 4; r0 < B_; r0 += 2048) {
        const int r = r0 + rsub;
        const int id = ids[r * F_ + f];
        const float4 v = *(const float4*)(fbase + (size_t)id * E_);
        const int d = dom[r];
        unsigned p0 = (unsigned)f2bf(v.x) | ((unsigned)f2bf(v.y) << 16);
        unsigned p1 = (unsigned)f2bf(v.z) | ((unsigned)f2bf(v.w) << 16);
        *(uint2*)(emb + (size_t)r * I_ + slot * 4) = make_uint2(p0, p1);
#pragma unroll
        for (int dd = 0; dd < 4; ++dd) {
            const float m = (d == dd) ? 1.f : 0.f;
            sa[dd][0] = fmaf(m, v.x, sa[dd][0]); qa[dd][0] = fmaf(m * v.x, v.x, qa[dd][0]);
            sa[dd][1] = fmaf(m, v.y, sa[dd][1]); qa[dd][1] = fmaf(m * v.y, v.y, qa[dd][1]);
            sa[dd][2] = fmaf(m, v.z, sa[dd][2]); qa[dd][2] = fmaf(m * v.z, v.z, qa[dd][2]);
            sa[dd][3] = fmaf(m, v.w, sa[dd][3]); qa[dd][3] = fmaf(m * v.w, v.w, qa[dd][3]);
        }
    }
    __shared__ float red[2][128][36];
    if (rsub >= 2) {
        float* p = red[rsub - 2][slot];
#pragma unroll
        for (int d = 0; d < 4; ++d)
#pragma unroll
            for (int c = 0; c < 4; ++c) { p[d * 4 + c] = sa[d][c]; p[16 + d * 4 + c] = qa[d][c]; }
    }
    __syncthreads();
    if (rsub < 2) {
        float* p = red[rsub][slot];
#pragma unroll
        for (int d = 0; d < 4; ++d)
#pragma unroll
            for (int c = 0; c < 4; ++c) { sa[d][c] += p[d * 4 + c]; qa[d][c] += p[16 + d * 4 + c]; }
    }
    __syncthreads();
    if (rsub == 1) {
        float* p = red[0][slot];
#pragma unroll
        for (int d = 0; d < 4; ++d)
#pragma unroll
            for (int c = 0; c < 4; ++c) { p[d * 4 + c] = sa[d][c]; p[16 + d * 4 + c] = qa[d][c]; }
    }
    __syncthreads();
    if (rsub == 0) {
        float* p = red[0][slot];
        const int g = blockIdx.x & 7;
#pragma unroll
        for (int d = 0; d < 4; ++d)
#pragma unroll
            for (int c = 0; c < 4; ++c) {
                atomicAdd(&S1G[g * 2048 + d * 512 + slot * 4 + c], sa[d][c] + p[d * 4 + c]);
                atomicAdd(&S2G[g * 2048 + d * 512 + slot * 4 + c], qa[d][c] + p[16 + d * 4 + c]);
            }
    }
}

// ---------- K2d: bucket rows by domain ----------
__global__ __launch_bounds__(256) void k_bucket(
    const int* __restrict__ dom, int* __restrict__ cnt, int* __restrict__ rl)
{
    const int r = blockIdx.x * 256 + threadIdx.x;
    const int d = dom[r];
    const int lane = threadIdx.x & 63;
#pragma unroll
    for (int dd = 0; dd < 4; ++dd) {
        unsigned long long mask = __ballot(d == dd);
        if (d == dd) {
            int lead = __ffsll((unsigned long long)mask) - 1;
            int pos = 0;
            if (lane == lead) pos = atomicAdd(&cnt[dd], __popcll(mask));
            pos = __shfl(pos, lead);
            pos += __popcll(mask & ((1ull << lane) - 1ull));
            rl[dd * B_ + pos] = r;
        }
    }
}

// ---------- K2a: finalize BN statistics (sums the 8 accumulator groups) ----------
__global__ __launch_bounds__(512) void k_stats(
    const float* __restrict__ S1G, const float* __restrict__ S2G, const int* __restrict__ cnt,
    const float* __restrict__ dw, const float* __restrict__ db,
    float* __restrict__ m_, float* __restrict__ dq, float* __restrict__ mu, float* __restrict__ isg)
{
    const int i = threadIdx.x;
    float nd[4], s1v[4], s2v[4], wv[4], bv[4];
#pragma unroll
    for (int d = 0; d < 4; ++d) {
        nd[d] = (float)cnt[d];
        float a = 0.f, b = 0.f;
#pragma unroll
        for (int g = 0; g < 8; ++g) {
            a += S1G[g * 2048 + d * 512 + i];
            b += S2G[g * 2048 + d * 512 + i];
        }
        s1v[d] = a; s2v[d] = b;
        wv[d] = dw[d * I_ + i];  bv[d] = db[d * I_ + i];
    }
    const float invB = 1.0f / (float)B_;
    float tot1 = s1v[0] + s1v[1] + s1v[2] + s1v[3];
    float tot2 = s2v[0] + s2v[1] + s2v[2] + s2v[3];
    float m = tot1 * invB;
    float v = fmaxf(tot2 * invB - m * m, 0.f);
    m_[i] = m;
#pragma unroll
    for (int d = 0; d < 4; ++d)
        dq[d * I_ + i] = wv[d] / sqrtf(v * wv[d] * wv[d] + EPS_);
    float ssum = 0.f, ssq = 0.f;
#pragma unroll
    for (int d = 0; d < 4; ++d) {
        ssum += wv[d] * s1v[d] + nd[d] * bv[d];
        ssq  += wv[d] * wv[d] * s2v[d] + 2.f * wv[d] * bv[d] * s1v[d] + nd[d] * bv[d] * bv[d];
    }
    float muv = ssum * invB;
    float var = fmaxf(ssq * invB - muv * muv, 0.f);
    mu[i] = muv;
    isg[i] = 1.f / sqrtf(var + EPS_);
}

// ---------- K2b: fold expert weights into MFMA-B-fragment-packed bf16 hi/lo ----------
// MB layout: ((((d*12+ct)*16+ic)*2+part)*64 + lane)*8 + j   (bf16)
// B-fragment map for mfma_f32_16x16x32_bf16: lane supplies B[(lane>>4)*8+j][lane&15].
__global__ __launch_bounds__(256) void k_foldM(
    const float* __restrict__ dw, const float* __restrict__ isg, const float* __restrict__ dq,
    const float* __restrict__ shg, const float* __restrict__ shW,
    const float* __restrict__ spg, const float* __restrict__ spW,
    const float* __restrict__ gW, unsigned short* __restrict__ MB)
{
    const int d = blockIdx.y;
    const int ct = blockIdx.x >> 4, ic = blockIdx.x & 15;
    const int t = threadIdx.x;
    const int lane = t >> 2, jp = t & 3;
    const int c = ct * 16 + (lane & 15);
    unsigned short hi2[2], lo2[2];
#pragma unroll
    for (int jj = 0; jj < 2; ++jj) {
        const int i = ic * 32 + (lane >> 4) * 8 + jp * 2 + jj;
        float val = 0.f;
        if (c < 128) {
            const int s = c >> 4, o = c & 15;
            val = dw[d * I_ + i] * isg[i] * shg[s * I_ + i] * shW[((size_t)s * I_ + i) * OUT_ + o];
        } else if (c < 160) {
            const int k = (c - 128) >> 4, o = c & 15;
            val = dq[d * I_ + i] * spg[((size_t)(d * K_ + k)) * I_ + i]
                * spW[(((size_t)(d * K_ + k)) * I_ + i) * OUT_ + o];
        } else if (c < 170) {
            val = dw[d * I_ + i] * gW[i * SK_ + (c - 160)];
        }
        unsigned short h = f2bf(val);
        float hv = __uint_as_float((unsigned)h << 16);
        hi2[jj] = h;
        lo2[jj] = f2bf(val - hv);
    }
    const size_t base = (((size_t)(d * 12 + ct) * 16 + ic) * 2) * 512 + lane * 8 + jp * 2;
    *(ushort2*)(MB + base)       = make_ushort2(hi2[0], hi2[1]);
    *(ushort2*)(MB + base + 512) = make_ushort2(lo2[0], lo2[1]);
}

// ---------- K2c: fold biases (f32 path, unchanged) ----------
__global__ __launch_bounds__(256) void k_foldB(
    const float* __restrict__ m_, const float* __restrict__ dq,
    const float* __restrict__ mu, const float* __restrict__ isg,
    const float* __restrict__ db,
    const float* __restrict__ shg, const float* __restrict__ shb_, const float* __restrict__ shW,
    const float* __restrict__ shb2,
    const float* __restrict__ spg, const float* __restrict__ spb_, const float* __restrict__ spW,
    const float* __restrict__ spb2,
    const float* __restrict__ gW, const float* __restrict__ gb, float* __restrict__ bias)
{
    const int d = blockIdx.y, e = blockIdx.x, t = threadIdx.x;
    __shared__ float red[256][17];
    float acc[16];
#pragma unroll
    for (int o = 0; o < 16; ++o) acc[o] = 0.f;

    if (e < 8) {
        for (int i = t; i < I_; i += 256) {
            float coef = (db[d * I_ + i] - mu[i]) * isg[i] * shg[e * I_ + i] + shb_[e * I_ + i];
            const float* wp = &shW[((size_t)e * I_ + i) * OUT_];
#pragma unroll
            for (int o = 0; o < 16; ++o) acc[o] += coef * wp[o];
        }
    } else if (e < 10) {
        const int k = e - 8;
        for (int i = t; i < I_; i += 256) {
            float coef = -m_[i] * dq[d * I_ + i] * spg[((size_t)(d * K_ + k)) * I_ + i]
                       + spb_[((size_t)(d * K_ + k)) * I_ + i];
            const float* wp = &spW[(((size_t)(d * K_ + k)) * I_ + i) * OUT_];
#pragma unroll
            for (int o = 0; o < 16; ++o) acc[o] += coef * wp[o];
        }
    } else {
        for (int i = t; i < I_; i += 256) {
            float bb = db[d * I_ + i];
#pragma unroll
            for (int g = 0; g < 10; ++g) acc[g] += bb * gW[i * SK_ + g];
        }
    }
#pragma unroll
    for (int o = 0; o < 16; ++o) red[t][o] = acc[o];
    __syncthreads();
    for (int st = 128; st > 0; st >>= 1) {
        if (t < st) {
#pragma unroll
            for (int o = 0; o < 16; ++o) red[t][o] += red[t + st][o];
        }
        __syncthreads();
    }
    if (t == 0) {
        if (e < 8) {
            for (int o = 0; o < 16; ++o) bias[d * C_ + e * 16 + o] = red[0][o] + shb2[e * 16 + o];
        } else if (e < 10) {
            const int k = e - 8;
            for (int o = 0; o < 16; ++o)
                bias[d * C_ + 128 + k * 16 + o] = red[0][o] + spb2[(d * K_ + k) * 16 + o];
        } else {
            for (int g = 0; g < 10; ++g) bias[d * C_ + 160 + g] = red[0][g] + gb[g];
            for (int c = 170; c < C_; ++c) bias[d * C_ + c] = 0.f;
        }
    }
}

// ---------- K3: MFMA GEMM + softmax gate + mix + MLP layer 1 ----------
// 512 threads = 8 waves: wave w -> row-tile (w&3), col-half (w>>2) of 64x192.
__global__ __launch_bounds__(512) void k_main(
    const unsigned short* __restrict__ emb, const int* __restrict__ rl, const int* __restrict__ cnt,
    const unsigned short* __restrict__ MB, const float* __restrict__ bias,
    const float* __restrict__ W1, const float* __restrict__ b1,
    float* __restrict__ h1g, float* __restrict__ h1s, float* __restrict__ h1q)
{
    const int d = blockIdx.y, tile = blockIdx.x;
    const int base = tile * 64;
    const int rem = cnt[d] - base;
    if (rem <= 0) return;
    const int nn = rem < 64 ? rem : 64;
    const int t = threadIdx.x;

    __shared__ int rid[64];
    __shared__ float smem[64 * OSTR + 64 * 33];
    float* obuf  = smem;
    float* h1buf = smem + 64 * OSTR;

    if (t < 64) rid[t] = rl[d * B_ + base + (t < nn ? t : nn - 1)];
    __syncthreads();

    const int wv = t >> 6, lane = t & 63;
    const int rt = wv & 3, ch = wv >> 2;       // row-tile 0..3, col-half 0..1
    const int l15 = lane & 15, lk = lane >> 4;

    const unsigned short* arow  = emb + (size_t)rid[rt * 16 + l15] * I_ + lk * 8;
    const unsigned short* bbase = MB + (size_t)d * 196608 + (size_t)ch * 98304 + lane * 8;

    f32x4 acc[6];
#pragma unroll
    for (int c6 = 0; c6 < 6; ++c6) acc[c6] = (f32x4){0.f, 0.f, 0.f, 0.f};

#pragma unroll 2
    for (int ic = 0; ic < 16; ++ic) {
        const bf16x8 a = *(const bf16x8*)(arow + ic * 32);
#pragma unroll
        for (int c6 = 0; c6 < 6; ++c6) {
            const unsigned short* bp = bbase + (size_t)c6 * 16384 + ic * 1024;
            const bf16x8 bh = *(const bf16x8*)bp;
            const bf16x8 bl = *(const bf16x8*)(bp + 512);
            acc[c6] = __builtin_amdgcn_mfma_f32_16x16x32_bf16(a, bh, acc[c6], 0, 0, 0);
            acc[c6] = __builtin_amdgcn_mfma_f32_16x16x32_bf16(a, bl, acc[c6], 0, 0, 0);
        }
    }

    // spill: D row=(lane>>4)*4+j, col=lane&15 within 16x16 tile
    const float* bd = bias + d * C_;
#pragma unroll
    for (int c6 = 0; c6 < 6; ++c6) {
        const int col = ch * 96 + c6 * 16 + l15;
        const float bv = bd[col];
#pragma unroll
        for (int j = 0; j < 4; ++j) {
            const int row = rt * 16 + lk * 4 + j;
            obuf[row * OSTR + col] = acc[c6][j] + bv;
        }
    }
    __syncthreads();

    // per-row: softmax gate, mix, h1 = mix@W1+b1
    if (t < 64) {
        const float* row = &obuf[t * OSTR];
        float g[10];
        float mx = row[160];
#pragma unroll
        for (int e = 1; e < 10; ++e) mx = fmaxf(mx, row[160 + e]);
        float ssum = 0.f;
#pragma unroll
        for (int e = 0; e < 10; ++e) { g[e] = __expf(row[160 + e] - mx); ssum += g[e]; }
        const float inv = 1.f / ssum;
        float mix[16];
#pragma unroll
        for (int o = 0; o < 16; ++o) mix[o] = 0.f;
#pragma unroll
        for (int e = 0; e < 10; ++e) {
#pragma unroll
            for (int o = 0; o < 16; ++o) mix[o] = fmaf(g[e], row[e * 16 + o], mix[o]);
        }
#pragma unroll
        for (int o = 0; o < 16; ++o) mix[o] *= inv;
#pragma unroll
        for (int o2 = 0; o2 < 32; ++o2) {
            float a = b1[o2];
#pragma unroll
            for (int o = 0; o < 16; ++o) a = fmaf(mix[o], W1[o * 32 + o2], a);
            h1buf[t * 33 + o2] = a;
        }
    }
    __syncthreads();
    if (t < 32) {
        float s = 0.f, q = 0.f;
        for (int r = 0; r < nn; ++r) { float v = h1buf[r * 33 + t]; s += v; q += v * v; }
        atomicAdd(&h1s[t], s); atomicAdd(&h1q[t], q);
    }
#pragma unroll
    for (int k = 0; k < 4; ++k) {
        const int idx = k * 512 + t;
        const int r = idx >> 5, c = idx & 31;
        if (r < nn) h1g[(size_t)rid[r] * 32 + c] = h1buf[r * 33 + c];
    }
}

// ---------- K4: BN+ReLU -> x@W2+b2, accumulate h2 stats ----------
__global__ __launch_bounds__(256) void k_mlp1(
    const float* __restrict__ h1g, const float* __restrict__ s1, const float* __restrict__ s2,
    const float* __restrict__ g1, const float* __restrict__ be1,
    const float* __restrict__ W2, const float* __restrict__ b2,
    float* __restrict__ h2g, float* __restrict__ h2s, float* __restrict__ h2q)
{
    __shared__ float hb[64 * 33];
    __shared__ float ab[64 * 33];
    __shared__ float w2t[32 * 32];   // [o][i]
    __shared__ float scl[32], shf[32];
    const int t = threadIdx.x;
    const size_t rb = (size_t)blockIdx.x * 64;
#pragma unroll
    for (int k = 0; k < 2; ++k) {
        const int w = k * 1024 + t * 4;
        const int r = w >> 5, c = w & 31;
        *(float4*)&hb[r * 33 + c] = *(const float4*)&h1g[rb * 32 + w];
    }
#pragma unroll
    for (int k = 0; k < 4; ++k) {
        const int idx = k * 256 + t;
        const int i = idx >> 5, o = idx & 31;
        w2t[o * 32 + i] = W2[idx];
    }
    if (t < 32) {
        const float invB = 1.0f / (float)B_;
        float mn = s1[t] * invB;
        float vr = fmaxf(s2[t] * invB - mn * mn, 0.f);
        float iv = 1.f / sqrtf(vr + EPS_);
        scl[t] = iv * g1[t]; shf[t] = be1[t] - mn * iv * g1[t];
    }
    __syncthreads();
    const int r = t >> 2, sub = t & 3;
#pragma unroll
    for (int k = 0; k < 8; ++k) {
        const int i = sub * 8 + k;
        float x = hb[r * 33 + i] * scl[i] + shf[i];
        ab[r * 33 + i] = fmaxf(x, 0.f);
    }
    __syncthreads();
    float h2[8];
#pragma unroll
    for (int kk = 0; kk < 8; ++kk) {
        const int o = sub * 8 + kk;
        float acc = b2[o];
#pragma unroll
        for (int i = 0; i < 32; i += 4) {
            const float4 w4 = *(const float4*)&w2t[o * 32 + i];
            acc = fmaf(ab[r * 33 + i], w4.x, acc);
            acc = fmaf(ab[r * 33 + i + 1], w4.y, acc);
            acc = fmaf(ab[r * 33 + i + 2], w4.z, acc);
            acc = fmaf(ab[r * 33 + i + 3], w4.w, acc);
        }
        h2[kk] = acc;
    }
    __syncthreads();
#pragma unroll
    for (int kk = 0; kk < 8; ++kk) hb[r * 33 + sub * 8 + kk] = h2[kk];
    __syncthreads();
    if (t < 32) {
        float s = 0.f, q = 0.f;
        for (int rr = 0; rr < 64; ++rr) { float v = hb[rr * 33 + t]; s += v; q += v * v; }
        atomicAdd(&h2s[t], s); atomicAdd(&h2q[t], q);
    }
#pragma unroll
    for (int k = 0; k < 2; ++k) {
        const int w = k * 1024 + t * 4;
        const int r2 = w >> 5, c = w & 31;
        *(float4*)&h2g[rb * 32 + w] = *(const float4*)&hb[r2 * 33 + c];
    }
}

// ---------- K5: BN+ReLU -> x@W3+b3 -> sigmoid ----------
__global__ __launch_bounds__(256) void k_mlp2(
    const float* __restrict__ h2g, const float* __restrict__ s1, const float* __restrict__ s2,
    const float* __restrict__ g2, const float* __restrict__ be2,
    const float* __restrict__ W3, const float* __restrict__ b3, float* __restrict__ out)
{
    __shared__ float hb[64 * 33];
    __shared__ float scl[32], shf[32], w3s[32];
    const int t = threadIdx.x;
    const size_t rb = (size_t)blockIdx.x * 64;
#pragma unroll
    for (int k = 0; k < 2; ++k) {
        const int w = k * 1024 + t * 4;
        const int r = w >> 5, c = w & 31;
        *(float4*)&hb[r * 33 + c] = *(const float4*)&h2g[rb * 32 + w];
    }
    if (t < 32) {
        const float invB = 1.0f / (float)B_;
        float mn = s1[t] * invB;
        float vr = fmaxf(s2[t] * invB - mn * mn, 0.f);
        float iv = 1.f / sqrtf(vr + EPS_);
        scl[t] = iv * g2[t]; shf[t] = be2[t] - mn * iv * g2[t];
        w3s[t] = W3[t];
    }
    __syncthreads();
    if (t < 64) {
        float acc = b3[0];
#pragma unroll
        for (int i = 0; i < 32; ++i) {
            float x = hb[t * 33 + i] * scl[i] + shf[i];
            x = fmaxf(x, 0.f);
            acc = fmaf(x, w3s[i], acc);
        }
        out[rb + t] = 1.f / (1.f + __expf(-acc));
    }
}

// ---------- launch ----------
extern "C" void kernel_launch(void* const* d_in, const int* in_sizes, int n_in,
                              void* d_out, int out_size, void* d_ws, size_t ws_size,
                              hipStream_t stream) {
    const int*   ids  = (const int*)d_in[0];
    const int*   dom  = (const int*)d_in[1];
    const float* tbl  = (const float*)d_in[2];
    const float* dw   = (const float*)d_in[3];
    const float* db   = (const float*)d_in[4];
    const float* shg  = (const float*)d_in[5];
    const float* shb_ = (const float*)d_in[6];
    const float* shW  = (const float*)d_in[7];
    const float* shb2 = (const float*)d_in[8];
    const float* spg  = (const float*)d_in[9];
    const float* spb_ = (const float*)d_in[10];
    const float* spW  = (const float*)d_in[11];
    const float* spb2 = (const float*)d_in[12];
    const float* gW   = (const float*)d_in[13];
    const float* gb   = (const float*)d_in[14];
    const float* W1   = (const float*)d_in[15];
    const float* b1   = (const float*)d_in[16];
    const float* g1   = (const float*)d_in[17];
    const float* be1  = (const float*)d_in[18];
    const float* W2   = (const float*)d_in[19];
    const float* b2   = (const float*)d_in[20];
    const float* g2   = (const float*)d_in[21];
    const float* be2  = (const float*)d_in[22];
    const float* W3   = (const float*)d_in[23];
    const float* b3   = (const float*)d_in[24];
    float* out = (float*)d_out;

    float* ws = (float*)d_ws;
    float* S1G  = ws + 0;          // 8*2048 = 16384
    float* S2G  = ws + 16384;      // 16384
    float* H1S  = ws + 32768;      // 32
    float* H1Q  = ws + 32800;      // 32
    float* H2S  = ws + 32832;      // 32
    float* H2Q  = ws + 32864;      // 32
    int*   CNT  = (int*)(ws + 32896);   // 4 ints
    float* M0v  = ws + 32960;      // 512
    float* DQ   = ws + 33472;      // 2048
    float* MU   = ws + 35520;      // 512
    float* ISG  = ws + 36032;      // 512
    float* BIASW= ws + 36544;      // 768
    unsigned short* MB = (unsigned short*)(ws + 37312);   // 786432 bf16 = 393216 floats
    int*   RL   = (int*)(ws + 430528);                    // 65536 ints
    unsigned short* EMB = (unsigned short*)(ws + 496064); // 16384*512 bf16 = 4194304 floats
    float* H1G  = ws + 4690368;    // 524288
    float* H2G  = ws + 5214656;    // 524288

    // zero accumulators (S1G,S2G,h-stats,CNT)
    hipMemsetAsync(d_ws, 0, 131600, stream);

    k_gather<<<512, 512, 0, stream>>>(ids, dom, tbl, EMB, S1G, S2G);
    k_bucket<<<64, 256, 0, stream>>>(dom, CNT, RL);
    k_stats<<<1, 512, 0, stream>>>(S1G, S2G, CNT, dw, db, M0v, DQ, MU, ISG);
    k_foldM<<<dim3(192, 4), 256, 0, stream>>>(dw, ISG, DQ, shg, shW, spg, spW, gW, MB);
    k_foldB<<<dim3(11, 4), 256, 0, stream>>>(M0v, DQ, MU, ISG, db, shg, shb_, shW, shb2,
                                             spg, spb_, spW, spb2, gW, gb, BIASW);
    k_main<<<dim3(256, 4), 512, 0, stream>>>(EMB, RL, CNT, MB, BIASW, W1, b1, H1G, H1S, H1Q);
    k_mlp1<<<256, 256, 0, stream>>>(H1G, H1S, H1Q, g1, be1, W2, b2, H2G, H2S, H2Q);
    k_mlp2<<<256, 256, 0, stream>>>(H2G, H2S, H2Q, g2, be2, W3, b3, out);
}

// Round 4
// 382.962 us; speedup vs baseline: 1.2764x; 1.0524x over previous
//
#include <hip/hip_runtime.h>
#include <hip/hip_bf16.h>

// Problem constants
#define B_    16384
#define F_    32
#define E_    16
#define V_    100000
#define D_    4
#define S_    8
#define K_    2
#define I_    512
#define OUT_  16
#define SK_   10
#define C_    192      // padded fold-matrix columns (160 expert outs + 10 gate + 22 pad)
#define OSTR  193      // obuf LDS row stride (conflict-free)
#define EPS_  1e-5f
#define NG    16       // stat accumulator groups (atomic contention divider)

typedef __attribute__((ext_vector_type(4))) float f32x4;
typedef __attribute__((ext_vector_type(8))) short bf16x8;

// ---------- helpers ----------
__device__ __forceinline__ unsigned short f2bf(float x) {
    unsigned u = __float_as_uint(x);
    unsigned r = (u + 0x7fffu + ((u >> 16) & 1u)) >> 16;
    return (unsigned short)r;
}

// ---------- K1: embedding gather + per-domain moment accumulation ----------
// 512 blocks x 512 threads; 8 iterations FULLY UNROLLED with phase-split loads
// (all ids issued, then all gathers in flight -> ~2 exposed latencies, not 16).
__global__ __launch_bounds__(512) void k_gather(
    const int* __restrict__ ids, const int* __restrict__ dom,
    const float* __restrict__ tbl, unsigned short* __restrict__ emb,
    float* __restrict__ S1G, float* __restrict__ S2G)
{
    const int t = threadIdx.x;
    const int slot = t & 127;     // owns cols slot*4 .. slot*4+3
    const int rsub = t >> 7;      // 0..3
    const int f = slot >> 2;
    const int e0 = (slot & 3) << 2;
    const int rbase = blockIdx.x * 4 + rsub;
    const float* fbase = tbl + (size_t)f * V_ * E_ + e0;

    int idv[8];
#pragma unroll
    for (int it = 0; it < 8; ++it)
        idv[it] = ids[(rbase + it * 2048) * F_ + f];
    float4 v[8];
#pragma unroll
    for (int it = 0; it < 8; ++it)
        v[it] = *(const float4*)(fbase + (size_t)idv[it] * E_);
    int dv[8];
#pragma unroll
    for (int it = 0; it < 8; ++it)
        dv[it] = dom[rbase + it * 2048];

    float sa[4][4], qa[4][4];
#pragma unroll
    for (int d = 0; d < 4; ++d)
#pragma unroll
        for (int c = 0; c < 4; ++c) { sa[d][c] = 0.f; qa[d][c] = 0.f; }

#pragma unroll
    for (int it = 0; it < 8; ++it) {
        const int r = rbase + it * 2048;
        unsigned p0 = (unsigned)f2bf(v[it].x) | ((unsigned)f2bf(v[it].y) << 16);
        unsigned p1 = (unsigned)f2bf(v[it].z) | ((unsigned)f2bf(v[it].w) << 16);
        *(uint2*)(emb + (size_t)r * I_ + slot * 4) = make_uint2(p0, p1);
        const int d = dv[it];
#pragma unroll
        for (int dd = 0; dd < 4; ++dd) {
            const float m = (d == dd) ? 1.f : 0.f;
            sa[dd][0] = fmaf(m, v[it].x, sa[dd][0]); qa[dd][0] = fmaf(m * v[it].x, v[it].x, qa[dd][0]);
            sa[dd][1] = fmaf(m, v[it].y, sa[dd][1]); qa[dd][1] = fmaf(m * v[it].y, v[it].y, qa[dd][1]);
            sa[dd][2] = fmaf(m, v[it].z, sa[dd][2]); qa[dd][2] = fmaf(m * v[it].z, v[it].z, qa[dd][2]);
            sa[dd][3] = fmaf(m, v[it].w, sa[dd][3]); qa[dd][3] = fmaf(m * v[it].w, v[it].w, qa[dd][3]);
        }
    }

    __shared__ float red[2][128][36];
    if (rsub >= 2) {
        float* p = red[rsub - 2][slot];
#pragma unroll
        for (int d = 0; d < 4; ++d)
#pragma unroll
            for (int c = 0; c < 4; ++c) { p[d * 4 + c] = sa[d][c]; p[16 + d * 4 + c] = qa[d][c]; }
    }
    __syncthreads();
    if (rsub < 2) {
        float* p = red[rsub][slot];
#pragma unroll
        for (int d = 0; d < 4; ++d)
#pragma unroll
            for (int c = 0; c < 4; ++c) { sa[d][c] += p[d * 4 + c]; qa[d][c] += p[16 + d * 4 + c]; }
    }
    __syncthreads();
    if (rsub == 1) {
        float* p = red[0][slot];
#pragma unroll
        for (int d = 0; d < 4; ++d)
#pragma unroll
            for (int c = 0; c < 4; ++c) { p[d * 4 + c] = sa[d][c]; p[16 + d * 4 + c] = qa[d][c]; }
    }
    __syncthreads();
    if (rsub == 0) {
        float* p = red[0][slot];
        const int g = blockIdx.x & (NG - 1);
#pragma unroll
        for (int d = 0; d < 4; ++d)
#pragma unroll
            for (int c = 0; c < 4; ++c) {
                atomicAdd(&S1G[(g * 4 + d) * 512 + slot * 4 + c], sa[d][c] + p[d * 4 + c]);
                atomicAdd(&S2G[(g * 4 + d) * 512 + slot * 4 + c], qa[d][c] + p[16 + d * 4 + c]);
            }
    }
}

// ---------- K2d: bucket rows by domain (block-aggregated: 4 atomics/block) ----------
__global__ __launch_bounds__(256) void k_bucket(
    const int* __restrict__ dom, int* __restrict__ cnt, int* __restrict__ rl)
{
    const int t = threadIdx.x;
    const int r = blockIdx.x * 256 + t;
    const int d = dom[r];
    const int wv = t >> 6;
    const int lane = t & 63;
    __shared__ int wcnt[4][4];   // [domain][wave]
    int myoff = 0;
#pragma unroll
    for (int dd = 0; dd < 4; ++dd) {
        unsigned long long m = __ballot(d == dd);
        if (lane == 0) wcnt[dd][wv] = (int)__popcll(m);
        if (d == dd) myoff = (int)__popcll(m & ((1ull << lane) - 1ull));
    }
    __syncthreads();
    if (t < 4) {
        int c0 = wcnt[t][0], c1 = wcnt[t][1], c2 = wcnt[t][2], c3 = wcnt[t][3];
        int b = atomicAdd(&cnt[t], c0 + c1 + c2 + c3);
        wcnt[t][0] = b; wcnt[t][1] = b + c0; wcnt[t][2] = b + c0 + c1; wcnt[t][3] = b + c0 + c1 + c2;
    }
    __syncthreads();
    rl[d * B_ + wcnt[d][wv] + myoff] = r;
}

// ---------- K2a: finalize BN statistics (2 blocks, sums NG groups) ----------
__global__ __launch_bounds__(256) void k_stats(
    const float* __restrict__ S1G, const float* __restrict__ S2G, const int* __restrict__ cnt,
    const float* __restrict__ dw, const float* __restrict__ db,
    float* __restrict__ m_, float* __restrict__ dq, float* __restrict__ mu, float* __restrict__ isg)
{
    const int i = blockIdx.x * 256 + threadIdx.x;
    float nd[4], s1v[4], s2v[4], wv[4], bv[4];
#pragma unroll
    for (int d = 0; d < 4; ++d) {
        nd[d] = (float)cnt[d];
        float a = 0.f, b = 0.f;
#pragma unroll
        for (int g = 0; g < NG; ++g) {
            a += S1G[(g * 4 + d) * 512 + i];
            b += S2G[(g * 4 + d) * 512 + i];
        }
        s1v[d] = a; s2v[d] = b;
        wv[d] = dw[d * I_ + i];  bv[d] = db[d * I_ + i];
    }
    const float invB = 1.0f / (float)B_;
    float tot1 = s1v[0] + s1v[1] + s1v[2] + s1v[3];
    float tot2 = s2v[0] + s2v[1] + s2v[2] + s2v[3];
    float m = tot1 * invB;
    float v = fmaxf(tot2 * invB - m * m, 0.f);
    m_[i] = m;
#pragma unroll
    for (int d = 0; d < 4; ++d)
        dq[d * I_ + i] = wv[d] / sqrtf(v * wv[d] * wv[d] + EPS_);
    float ssum = 0.f, ssq = 0.f;
#pragma unroll
    for (int d = 0; d < 4; ++d) {
        ssum += wv[d] * s1v[d] + nd[d] * bv[d];
        ssq  += wv[d] * wv[d] * s2v[d] + 2.f * wv[d] * bv[d] * s1v[d] + nd[d] * bv[d] * bv[d];
    }
    float muv = ssum * invB;
    float var = fmaxf(ssq * invB - muv * muv, 0.f);
    mu[i] = muv;
    isg[i] = 1.f / sqrtf(var + EPS_);
}

// ---------- K2b: merged weight fold (x<192: M-fragments) + bias fold (x>=192) ----------
// MB layout: ((((d*12+ct)*16+ic)*2+part)*64 + lane)*8 + j   (bf16, hi/lo split)
__global__ __launch_bounds__(256) void k_fold(
    const float* __restrict__ dw, const float* __restrict__ isg, const float* __restrict__ dq,
    const float* __restrict__ shg, const float* __restrict__ shW,
    const float* __restrict__ spg, const float* __restrict__ spW,
    const float* __restrict__ gW, unsigned short* __restrict__ MB,
    const float* __restrict__ m_, const float* __restrict__ mu,
    const float* __restrict__ db,
    const float* __restrict__ shb_, const float* __restrict__ shb2,
    const float* __restrict__ spb_, const float* __restrict__ spb2,
    const float* __restrict__ gb, float* __restrict__ bias)
{
    const int d = blockIdx.y;
    const int t = threadIdx.x;
    if (blockIdx.x < 192) {
        const int ct = blockIdx.x >> 4, ic = blockIdx.x & 15;
        const int lane = t >> 2, jp = t & 3;
        const int c = ct * 16 + (lane & 15);
        unsigned short hi2[2], lo2[2];
#pragma unroll
        for (int jj = 0; jj < 2; ++jj) {
            const int i = ic * 32 + (lane >> 4) * 8 + jp * 2 + jj;
            float val = 0.f;
            if (c < 128) {
                const int s = c >> 4, o = c & 15;
                val = dw[d * I_ + i] * isg[i] * shg[s * I_ + i] * shW[((size_t)s * I_ + i) * OUT_ + o];
            } else if (c < 160) {
                const int k = (c - 128) >> 4, o = c & 15;
                val = dq[d * I_ + i] * spg[((size_t)(d * K_ + k)) * I_ + i]
                    * spW[(((size_t)(d * K_ + k)) * I_ + i) * OUT_ + o];
            } else if (c < 170) {
                val = dw[d * I_ + i] * gW[i * SK_ + (c - 160)];
            }
            unsigned short h = f2bf(val);
            float hv = __uint_as_float((unsigned)h << 16);
            hi2[jj] = h;
            lo2[jj] = f2bf(val - hv);
        }
        const size_t base = (((size_t)(d * 12 + ct) * 16 + ic) * 2) * 512 + lane * 8 + jp * 2;
        *(ushort2*)(MB + base)       = make_ushort2(hi2[0], hi2[1]);
        *(ushort2*)(MB + base + 512) = make_ushort2(lo2[0], lo2[1]);
        return;
    }
    // ---- bias fold ----
    const int e = blockIdx.x - 192;
    __shared__ float red[256][17];
    float acc[16];
#pragma unroll
    for (int o = 0; o < 16; ++o) acc[o] = 0.f;

    if (e < 8) {
        for (int i = t; i < I_; i += 256) {
            float coef = (db[d * I_ + i] - mu[i]) * isg[i] * shg[e * I_ + i] + shb_[e * I_ + i];
            const float* wp = &shW[((size_t)e * I_ + i) * OUT_];
#pragma unroll
            for (int o = 0; o < 16; ++o) acc[o] += coef * wp[o];
        }
    } else if (e < 10) {
        const int k = e - 8;
        for (int i = t; i < I_; i += 256) {
            float coef = -m_[i] * dq[d * I_ + i] * spg[((size_t)(d * K_ + k)) * I_ + i]
                       + spb_[((size_t)(d * K_ + k)) * I_ + i];
            const float* wp = &spW[(((size_t)(d * K_ + k)) * I_ + i) * OUT_];
#pragma unroll
            for (int o = 0; o < 16; ++o) acc[o] += coef * wp[o];
        }
    } else {
        for (int i = t; i < I_; i += 256) {
            float bb = db[d * I_ + i];
#pragma unroll
            for (int g = 0; g < 10; ++g) acc[g] += bb * gW[i * SK_ + g];
        }
    }
#pragma unroll
    for (int o = 0; o < 16; ++o) red[t][o] = acc[o];
    __syncthreads();
    for (int st = 128; st > 0; st >>= 1) {
        if (t < st) {
#pragma unroll
            for (int o = 0; o < 16; ++o) red[t][o] += red[t + st][o];
        }
        __syncthreads();
    }
    if (t == 0) {
        if (e < 8) {
            for (int o = 0; o < 16; ++o) bias[d * C_ + e * 16 + o] = red[0][o] + shb2[e * 16 + o];
        } else if (e < 10) {
            const int k = e - 8;
            for (int o = 0; o < 16; ++o)
                bias[d * C_ + 128 + k * 16 + o] = red[0][o] + spb2[(d * K_ + k) * 16 + o];
        } else {
            for (int g = 0; g < 10; ++g) bias[d * C_ + 160 + g] = red[0][g] + gb[g];
            for (int c = 170; c < C_; ++c) bias[d * C_ + c] = 0.f;
        }
    }
}

// ---------- K3: MFMA GEMM + softmax gate + mix + MLP layer 1 ----------
// 32-row tiles, 512 threads = 8 waves: rt = wv&1 (row half), ch = wv>>1 (col quarter).
__global__ __launch_bounds__(512) void k_main(
    const unsigned short* __restrict__ emb, const int* __restrict__ rl, const int* __restrict__ cnt,
    const unsigned short* __restrict__ MB, const float* __restrict__ bias,
    const float* __restrict__ W1, const float* __restrict__ b1,
    float* __restrict__ h1g, float* __restrict__ h1s, float* __restrict__ h1q)
{
    const int d = blockIdx.y, tile = blockIdx.x;
    const int base = tile * 32;
    const int rem = cnt[d] - base;
    if (rem <= 0) return;
    const int nn = rem < 32 ? rem : 32;
    const int t = threadIdx.x;

    __shared__ int rid[32];
    __shared__ float smem[32 * OSTR + 32 * 33];
    float* obuf  = smem;
    float* h1buf = smem + 32 * OSTR;

    if (t < 32) rid[t] = rl[d * B_ + base + (t < nn ? t : nn - 1)];
    __syncthreads();

    const int wv = t >> 6, lane = t & 63;
    const int rt = wv & 1, ch = wv >> 1;       // row-half 0..1, col-quarter 0..3
    const int l15 = lane & 15, lk = lane >> 4;

    const unsigned short* arow  = emb + (size_t)rid[rt * 16 + l15] * I_ + lk * 8;
    const unsigned short* bbase = MB + (size_t)d * 196608 + (size_t)(ch * 3) * 16384 + lane * 8;

    f32x4 acc[3];
#pragma unroll
    for (int c3 = 0; c3 < 3; ++c3) acc[c3] = (f32x4){0.f, 0.f, 0.f, 0.f};

#pragma unroll 4
    for (int ic = 0; ic < 16; ++ic) {
        const bf16x8 a = *(const bf16x8*)(arow + ic * 32);
#pragma unroll
        for (int c3 = 0; c3 < 3; ++c3) {
            const unsigned short* bp = bbase + (size_t)c3 * 16384 + ic * 1024;
            const bf16x8 bh = *(const bf16x8*)bp;
            const bf16x8 bl = *(const bf16x8*)(bp + 512);
            acc[c3] = __builtin_amdgcn_mfma_f32_16x16x32_bf16(a, bh, acc[c3], 0, 0, 0);
            acc[c3] = __builtin_amdgcn_mfma_f32_16x16x32_bf16(a, bl, acc[c3], 0, 0, 0);
        }
    }

    // spill: D row=(lane>>4)*4+j, col=lane&15 within 16x16 tile
    const float* bd = bias + d * C_;
#pragma unroll
    for (int c3 = 0; c3 < 3; ++c3) {
        const int col = ch * 48 + c3 * 16 + l15;
        const float bv = bd[col];
#pragma unroll
        for (int j = 0; j < 4; ++j) {
            const int row = rt * 16 + lk * 4 + j;
            obuf[row * OSTR + col] = acc[c3][j] + bv;
        }
    }
    __syncthreads();

    // per-row: softmax gate, mix, h1 = mix@W1+b1
    if (t < 32) {
        const float* row = &obuf[t * OSTR];
        float g[10];
        float mx = row[160];
#pragma unroll
        for (int e = 1; e < 10; ++e) mx = fmaxf(mx, row[160 + e]);
        float ssum = 0.f;
#pragma unroll
        for (int e = 0; e < 10; ++e) { g[e] = __expf(row[160 + e] - mx); ssum += g[e]; }
        const float inv = 1.f / ssum;
        float mix[16];
#pragma unroll
        for (int o = 0; o < 16; ++o) mix[o] = 0.f;
#pragma unroll
        for (int e = 0; e < 10; ++e) {
#pragma unroll
            for (int o = 0; o < 16; ++o) mix[o] = fmaf(g[e], row[e * 16 + o], mix[o]);
        }
#pragma unroll
        for (int o = 0; o < 16; ++o) mix[o] *= inv;
#pragma unroll
        for (int o2 = 0; o2 < 32; ++o2) {
            float a = b1[o2];
#pragma unroll
            for (int o = 0; o < 16; ++o) a = fmaf(mix[o], W1[o * 32 + o2], a);
            h1buf[t * 33 + o2] = a;
        }
    }
    __syncthreads();
    if (t < 32) {
        float s = 0.f, q = 0.f;
        for (int r = 0; r < nn; ++r) { float v = h1buf[r * 33 + t]; s += v; q += v * v; }
        const int g = (blockIdx.x + blockIdx.y) & (NG - 1);
        atomicAdd(&h1s[g * 32 + t], s); atomicAdd(&h1q[g * 32 + t], q);
    }
#pragma unroll
    for (int k = 0; k < 2; ++k) {
        const int idx = k * 512 + t;
        const int r = idx >> 5, c = idx & 31;
        if (r < nn) h1g[(size_t)rid[r] * 32 + c] = h1buf[r * 33 + c];
    }
}

// ---------- K4: BN+ReLU -> x@W2+b2, accumulate h2 stats ----------
__global__ __launch_bounds__(256) void k_mlp1(
    const float* __restrict__ h1g, const float* __restrict__ s1, const float* __restrict__ s2,
    const float* __restrict__ g1, const float* __restrict__ be1,
    const float* __restrict__ W2, const float* __restrict__ b2,
    float* __restrict__ h2g, float* __restrict__ h2s, float* __restrict__ h2q)
{
    __shared__ float hb[64 * 33];
    __shared__ float ab[64 * 33];
    __shared__ float w2t[32 * 32];   // [o][i]
    __shared__ float scl[32], shf[32];
    const int t = threadIdx.x;
    const size_t rb = (size_t)blockIdx.x * 64;
#pragma unroll
    for (int k = 0; k < 2; ++k) {
        const int w = k * 1024 + t * 4;
        const int r = w >> 5, c = w & 31;
        *(float4*)&hb[r * 33 + c] = *(const float4*)&h1g[rb * 32 + w];
    }
#pragma unroll
    for (int k = 0; k < 4; ++k) {
        const int idx = k * 256 + t;
        const int i = idx >> 5, o = idx & 31;
        w2t[o * 32 + i] = W2[idx];
    }
    if (t < 32) {
        float s = 0.f, q = 0.f;
#pragma unroll
        for (int g = 0; g < NG; ++g) { s += s1[g * 32 + t]; q += s2[g * 32 + t]; }
        const float invB = 1.0f / (float)B_;
        float mn = s * invB;
        float vr = fmaxf(q * invB - mn * mn, 0.f);
        float iv = 1.f / sqrtf(vr + EPS_);
        scl[t] = iv * g1[t]; shf[t] = be1[t] - mn * iv * g1[t];
    }
    __syncthreads();
    const int r = t >> 2, sub = t & 3;
#pragma unroll
    for (int k = 0; k < 8; ++k) {
        const int i = sub * 8 + k;
        float x = hb[r * 33 + i] * scl[i] + shf[i];
        ab[r * 33 + i] = fmaxf(x, 0.f);
    }
    __syncthreads();
    float h2[8];
#pragma unroll
    for (int kk = 0; kk < 8; ++kk) {
        const int o = sub * 8 + kk;
        float acc = b2[o];
#pragma unroll
        for (int i = 0; i < 32; i += 4) {
            const float4 w4 = *(const float4*)&w2t[o * 32 + i];
            acc = fmaf(ab[r * 33 + i], w4.x, acc);
            acc = fmaf(ab[r * 33 + i + 1], w4.y, acc);
            acc = fmaf(ab[r * 33 + i + 2], w4.z, acc);
            acc = fmaf(ab[r * 33 + i + 3], w4.w, acc);
        }
        h2[kk] = acc;
    }
    __syncthreads();
#pragma unroll
    for (int kk = 0; kk < 8; ++kk) hb[r * 33 + sub * 8 + kk] = h2[kk];
    __syncthreads();
    if (t < 32) {
        float s = 0.f, q = 0.f;
        for (int rr = 0; rr < 64; ++rr) { float v = hb[rr * 33 + t]; s += v; q += v * v; }
        const int g = blockIdx.x & (NG - 1);
        atomicAdd(&h2s[g * 32 + t], s); atomicAdd(&h2q[g * 32 + t], q);
    }
#pragma unroll
    for (int k = 0; k < 2; ++k) {
        const int w = k * 1024 + t * 4;
        const int r2 = w >> 5, c = w & 31;
        *(float4*)&h2g[rb * 32 + w] = *(const float4*)&hb[r2 * 33 + c];
    }
}

// ---------- K5: BN+ReLU -> x@W3+b3 -> sigmoid ----------
__global__ __launch_bounds__(256) void k_mlp2(
    const float* __restrict__ h2g, const float* __restrict__ s1, const float* __restrict__ s2,
    const float* __restrict__ g2, const float* __restrict__ be2,
    const float* __restrict__ W3, const float* __restrict__ b3, float* __restrict__ out)
{
    __shared__ float hb[64 * 33];
    __shared__ float scl[32], shf[32], w3s[32];
    const int t = threadIdx.x;
    const size_t rb = (size_t)blockIdx.x * 64;
#pragma unroll
    for (int k = 0; k < 2; ++k) {
        const int w = k * 1024 + t * 4;
        const int r = w >> 5, c = w & 31;
        *(float4*)&hb[r * 33 + c] = *(const float4*)&h2g[rb * 32 + w];
    }
    if (t < 32) {
        float s = 0.f, q = 0.f;
#pragma unroll
        for (int g = 0; g < NG; ++g) { s += s1[g * 32 + t]; q += s2[g * 32 + t]; }
        const float invB = 1.0f / (float)B_;
        float mn = s * invB;
        float vr = fmaxf(q * invB - mn * mn, 0.f);
        float iv = 1.f / sqrtf(vr + EPS_);
        scl[t] = iv * g2[t]; shf[t] = be2[t] - mn * iv * g2[t];
        w3s[t] = W3[t];
    }
    __syncthreads();
    if (t < 64) {
        float acc = b3[0];
#pragma unroll
        for (int i = 0; i < 32; ++i) {
            float x = hb[t * 33 + i] * scl[i] + shf[i];
            x = fmaxf(x, 0.f);
            acc = fmaf(x, w3s[i], acc);
        }
        out[rb + t] = 1.f / (1.f + __expf(-acc));
    }
}

// ---------- launch ----------
extern "C" void kernel_launch(void* const* d_in, const int* in_sizes, int n_in,
                              void* d_out, int out_size, void* d_ws, size_t ws_size,
                              hipStream_t stream) {
    const int*   ids  = (const int*)d_in[0];
    const int*   dom  = (const int*)d_in[1];
    const float* tbl  = (const float*)d_in[2];
    const float* dw   = (const float*)d_in[3];
    const float* db   = (const float*)d_in[4];
    const float* shg  = (const float*)d_in[5];
    const float* shb_ = (const float*)d_in[6];
    const float* shW  = (const float*)d_in[7];
    const float* shb2 = (const float*)d_in[8];
    const float* spg  = (const float*)d_in[9];
    const float* spb_ = (const float*)d_in[10];
    const float* spW  = (const float*)d_in[11];
    const float* spb2 = (const float*)d_in[12];
    const float* gW   = (const float*)d_in[13];
    const float* gb   = (const float*)d_in[14];
    const float* W1   = (const float*)d_in[15];
    const float* b1   = (const float*)d_in[16];
    const float* g1   = (const float*)d_in[17];
    const float* be1  = (const float*)d_in[18];
    const float* W2   = (const float*)d_in[19];
    const float* b2   = (const float*)d_in[20];
    const float* g2   = (const float*)d_in[21];
    const float* be2  = (const float*)d_in[22];
    const float* W3   = (const float*)d_in[23];
    const float* b3   = (const float*)d_in[24];
    float* out = (float*)d_out;

    float* ws = (float*)d_ws;
    float* S1G  = ws + 0;          // NG*4*512 = 32768
    float* S2G  = ws + 32768;      // 32768
    float* H1S  = ws + 65536;      // NG*32 = 512
    float* H1Q  = ws + 66048;      // 512
    float* H2S  = ws + 66560;      // 512
    float* H2Q  = ws + 67072;      // 512
    int*   CNT  = (int*)(ws + 67584);   // 4 ints
    float* M0v  = ws + 67600;      // 512
    float* DQ   = ws + 68112;      // 2048
    float* MU   = ws + 70160;      // 512
    float* ISG  = ws + 70672;      // 512
    float* BIASW= ws + 71184;      // 768
    unsigned short* MB = (unsigned short*)(ws + 71952);   // 786432 bf16 = 393216 floats
    int*   RL   = (int*)(ws + 465168);                    // 65536 ints
    unsigned short* EMB = (unsigned short*)(ws + 530704); // 16384*512 bf16 = 4194304 floats
    float* H1G  = ws + 4725008;    // 524288
    float* H2G  = ws + 5249296;    // 524288

    // zero accumulators (S1G,S2G,h-stats,CNT)
    hipMemsetAsync(d_ws, 0, 270400, stream);

    k_gather<<<512, 512, 0, stream>>>(ids, dom, tbl, EMB, S1G, S2G);
    k_bucket<<<64, 256, 0, stream>>>(dom, CNT, RL);
    k_stats<<<2, 256, 0, stream>>>(S1G, S2G, CNT, dw, db, M0v, DQ, MU, ISG);
    k_fold<<<dim3(203, 4), 256, 0, stream>>>(dw, ISG, DQ, shg, shW, spg, spW, gW, MB,
                                             M0v, MU, db, shb_, shb2, spb_, spb2, gb, BIASW);
    k_main<<<dim3(512, 4), 512, 0, stream>>>(EMB, RL, CNT, MB, BIASW, W1, b1, H1G, H1S, H1Q);
    k_mlp1<<<256, 256, 0, stream>>>(H1G, H1S, H1Q, g1, be1, W2, b2, H2G, H2S, H2Q);
    k_mlp2<<<256, 256, 0, stream>>>(H2G, H2S, H2Q, g2, be2, W3, b3, out);
}